// Round 1
// baseline (270.180 us; speedup 1.0000x reference)
//
#include <hip/hip_runtime.h>

// ---------------------------------------------------------------------------
// Attention (B=4, N=2048, DIM=1024, H=16, Dh=64) in fp16 MFMA, fp32 accum.
// Pipeline: cast/transpose -> GEMM(qkv, scattered epilogue) -> flash attn
//           -> GEMM(out proj + bias).
// R9: replace both 128x128 2-barrier GEMMs with an 8-phase counted-vmcnt
//     schedule (T3+T4+T5): BM=128 BN=256 BK=32, 512 thr / 8 waves (2Mx4N,
//     wave tile 64x64), 4 LDS K-tile buffers (96KB), prefetch K-tile t+3 via
//     global_load_lds, raw s_barrier + s_waitcnt vmcnt(6) (never 0 in main
//     loop) so the load queue survives barriers. qkv grid 768 = 3 exact
//     CU-rounds; out-proj grid 256 = 1 round. XOR chunk swizzle keeps
//     ds_read_b128 at 2-way (free). attn: + setprio around MFMA clusters.
// ---------------------------------------------------------------------------

typedef _Float16 half8 __attribute__((ext_vector_type(8)));
typedef __fp16 fp16v2 __attribute__((ext_vector_type(2)));
typedef float floatx4 __attribute__((ext_vector_type(4)));
typedef unsigned short u16;

struct __align__(8) U16x4 { u16 x, y, z, w; };

__device__ __forceinline__ u16 f2h(float f) {
  union { _Float16 h; u16 u; } cv;
  cv.h = (_Float16)f;
  return cv.u;
}

// async global->LDS, 16B per lane. LDS dest = wave-uniform base + lane*16.
__device__ __forceinline__ void g2l16(const void* g, void* l) {
  __builtin_amdgcn_global_load_lds(
      (const __attribute__((address_space(1))) void*)g,
      (__attribute__((address_space(3))) void*)l, 16, 0, 0);
}

// 2-bit chunk swizzle (4 chunks/row): slot c, row=c>>2 -> chunk^((row>>1)&3)
__device__ __forceinline__ int swz(int c) { return (c & 3) ^ ((c >> 3) & 3); }

// ---------------------------------------------------------------------------
// Kernel 1: flat cast fp32 -> fp16 (x). 8 elems/thread, exact coverage.
// ---------------------------------------------------------------------------
__global__ __launch_bounds__(256) void cast_f32_f16(const float* __restrict__ in,
                                                    u16* __restrict__ out) {
  long long base = ((long long)blockIdx.x * 256 + threadIdx.x) * 8;
  float4 a = *(const float4*)(in + base);
  float4 b = *(const float4*)(in + base + 4);
  U16x4 u0 = {f2h(a.x), f2h(a.y), f2h(a.z), f2h(a.w)};
  U16x4 u1 = {f2h(b.x), f2h(b.y), f2h(b.z), f2h(b.w)};
  *(U16x4*)(out + base) = u0;
  *(U16x4*)(out + base + 4) = u1;
}

// ---------------------------------------------------------------------------
// Kernel 2: transpose + cast. in [K][N] fp32 -> out [N][K] fp16. 64x64 tiles.
// ---------------------------------------------------------------------------
__global__ __launch_bounds__(256) void transpose_cast(const float* __restrict__ in,
                                                      u16* __restrict__ out,
                                                      int K, int N) {
  __shared__ u16 ls[64][72];
  const int nTK = K >> 6;
  const int tk = blockIdx.x % nTK;
  const int tn = blockIdx.x / nTK;
  const int tid = threadIdx.x;
#pragma unroll
  for (int i = 0; i < 4; ++i) {
    int idx = i * 256 + tid;
    int r = idx >> 4, c4 = (idx & 15) * 4;
    float4 v = *(const float4*)(in + (long long)(tk * 64 + r) * N + tn * 64 + c4);
    ls[r][c4 + 0] = f2h(v.x);
    ls[r][c4 + 1] = f2h(v.y);
    ls[r][c4 + 2] = f2h(v.z);
    ls[r][c4 + 3] = f2h(v.w);
  }
  __syncthreads();
#pragma unroll
  for (int i = 0; i < 4; ++i) {
    int idx = i * 256 + tid;
    int nr = idx >> 4, kc4 = (idx & 15) * 4;
    U16x4 u = {ls[kc4 + 0][nr], ls[kc4 + 1][nr], ls[kc4 + 2][nr], ls[kc4 + 3][nr]};
    *(U16x4*)(out + (long long)(tn * 64 + nr) * K + tk * 64 + kc4) = u;
  }
}

// ---------------------------------------------------------------------------
// Kernel 3/5: fp16 GEMM, C[M,N] = A[M,1024] @ Bt[N,1024]^T, 8-phase schedule.
//   BM=128, BN=256, BK=32, 32 K-tiles. 8 waves: wm=(w>>2)*64, wn=(w&3)*64.
//   LDS: lsA 4 bufs x 128x32 (32KB), lsB 4 bufs x 256x32 (64KB).
//   Per K-tile phase: read 4 A-frags + 4 B-frags (b128, XOR-swizzled),
//   issue 3 g2l16 for K-tile kt+3 (A:1, B:2 per thread, uniform per wave),
//   s_barrier; lgkmcnt(0); setprio(1); 16 MFMA; setprio(0); vmcnt(6); bar.
//   Steady-state per-wave outstanding = KT t+2 (3) + t+3 (3) = 6, so
//   vmcnt(6) proves KT t+1 landed. Tail: vmcnt(3) at kt=29, vmcnt(0) at 30.
//   EPI=0: scatter Q (pre-scaled), K, V^T.  EPI=1: fp32 + bias.
// ---------------------------------------------------------------------------
template <int EPI>
__global__ __launch_bounds__(512, 2) void gemm8p(const u16* __restrict__ A,
                                                 const u16* __restrict__ Bt,
                                                 u16* __restrict__ O0,
                                                 u16* __restrict__ O1,
                                                 u16* __restrict__ O2,
                                                 float* __restrict__ Of,
                                                 const float* __restrict__ bias) {
  __shared__ __attribute__((aligned(16))) u16 lsA[4 * 128 * 32];  // 32KB
  __shared__ __attribute__((aligned(16))) u16 lsB[4 * 256 * 32];  // 64KB
  const int tid = threadIdx.x;
  const int lane = tid & 63, wave = tid >> 6;
  const int l15 = lane & 15, quad = lane >> 4;
  // read-side swizzle: chunk' = quad ^ ((row>>1)&3); row bases are mult of 16
  const int offAB = (quad ^ ((l15 >> 1) & 3)) * 8;
  const int wm = (wave >> 2) * 64, wn = (wave & 3) * 64;
  constexpr int nwg = (EPI == 0) ? 768 : 256;  // 64x12 / 64x4 tiles
  // XCD swizzle (bijective: nwg % 8 == 0): contiguous work chunk per XCD
  const int b = (blockIdx.x & 7) * (nwg >> 3) + (blockIdx.x >> 3);
  const int bm = b & 63, bn = b >> 6;

  // staging source: dest row r = slot*16 + (lane>>2), dest chunk = lane&3;
  // source chunk = (lane&3) ^ ((r>>1)&3) = (lane&3) ^ ((lane>>3)&3)
  const int colsw = ((lane & 3) ^ ((lane >> 3) & 3)) * 8;
  const u16* gA =
      A + (long long)(bm * 128 + wave * 16 + (lane >> 2)) * 1024 + colsw;
  const u16* gB[2];
#pragma unroll
  for (int i = 0; i < 2; ++i)
    gB[i] = Bt + (long long)(bn * 256 + (wave * 2 + i) * 16 + (lane >> 2)) * 1024 +
            colsw;

  floatx4 acc[4][4] = {};

  // ---- prologue: stage K-tiles 0,1,2 into bufs 0,1,2 (9 loads/thread) ----
#pragma unroll
  for (int j = 0; j < 3; ++j) {
    g2l16(gA + j * 32, lsA + j * 4096 + wave * 512);
#pragma unroll
    for (int i = 0; i < 2; ++i)
      g2l16(gB[i] + j * 32, lsB + j * 8192 + (wave * 2 + i) * 512);
  }
  asm volatile("s_waitcnt vmcnt(6)");  // KT0 landed; KT1,2 in flight
  __builtin_amdgcn_s_barrier();

  // ---- main loop: 32 K-tiles, one phase each ----
  for (int kt = 0; kt < 32; ++kt) {
    const int cb = kt & 3;
    const u16* bA = lsA + cb * 4096;
    const u16* bB = lsB + cb * 8192;
    half8 af[4], bf[4];
#pragma unroll
    for (int mt = 0; mt < 4; ++mt)
      af[mt] = *(const half8*)(bA + (wm + mt * 16 + l15) * 32 + offAB);
#pragma unroll
    for (int nt = 0; nt < 4; ++nt)
      bf[nt] = *(const half8*)(bB + (wn + nt * 16 + l15) * 32 + offAB);
    if (kt < 29) {  // prefetch K-tile kt+3 into buf (kt+3)&3 (freed at kt-1)
      const int fb = (kt + 3) & 3;
      g2l16(gA + (kt + 3) * 32, lsA + fb * 4096 + wave * 512);
#pragma unroll
      for (int i = 0; i < 2; ++i)
        g2l16(gB[i] + (kt + 3) * 32, lsB + fb * 8192 + (wave * 2 + i) * 512);
    }
    __builtin_amdgcn_s_barrier();
    asm volatile("s_waitcnt lgkmcnt(0)");
    __builtin_amdgcn_s_setprio(1);
#pragma unroll
    for (int mt = 0; mt < 4; ++mt)
#pragma unroll
      for (int nt = 0; nt < 4; ++nt)
        acc[mt][nt] = __builtin_amdgcn_mfma_f32_16x16x32_f16(af[mt], bf[nt],
                                                             acc[mt][nt], 0, 0, 0);
    __builtin_amdgcn_s_setprio(0);
    if (kt < 29)
      asm volatile("s_waitcnt vmcnt(6)");  // KT kt+1 landed; kt+2,kt+3 in flight
    else if (kt == 29)
      asm volatile("s_waitcnt vmcnt(3)");  // KT30 landed; KT31 in flight
    else if (kt == 30)
      asm volatile("s_waitcnt vmcnt(0)");  // KT31 landed
    __builtin_amdgcn_s_barrier();
  }

  if (EPI == 0) {
    const float slq = 0.125f * 1.44269504088896f;  // SCALE*log2(e), folded into Q
#pragma unroll
    for (int mt = 0; mt < 4; ++mt) {
      int gm = bm * 128 + wm + mt * 16 + quad * 4;
      int bb = gm >> 11, n0 = gm & 2047;
#pragma unroll
      for (int nt = 0; nt < 4; ++nt) {
        int gc = bn * 256 + wn + nt * 16 + l15;
        int t = gc >> 10, hd = gc & 1023, h = hd >> 6, d = hd & 63;
        long long bh = (long long)(bb * 16 + h);
        if (t == 2) {
          U16x4 u = {f2h(acc[mt][nt][0]), f2h(acc[mt][nt][1]),
                     f2h(acc[mt][nt][2]), f2h(acc[mt][nt][3])};
          *(U16x4*)(O2 + (bh * 64 + d) * 2048 + n0) = u;
        } else {
          float s = (t == 0) ? slq : 1.0f;
          u16* dst = (t == 0 ? O0 : O1) + (bh * 2048 + n0) * 64 + d;
#pragma unroll
          for (int r = 0; r < 4; ++r) dst[r * 64] = f2h(acc[mt][nt][r] * s);
        }
      }
    }
  } else {
#pragma unroll
    for (int mt = 0; mt < 4; ++mt) {
      int gm = bm * 128 + wm + mt * 16 + quad * 4;
#pragma unroll
      for (int nt = 0; nt < 4; ++nt) {
        int gc = bn * 256 + wn + nt * 16 + l15;
        float bv = bias[gc];
#pragma unroll
        for (int r = 0; r < 4; ++r)
          Of[(long long)(gm + r) * 1024 + gc] = acc[mt][nt][r] + bv;
      }
    }
  }
}

// ---------------------------------------------------------------------------
// Kernel 4: flash attention. Wave owns 64 q (4 x 16-row MFMA tiles), q-tile
// 256/block, grid 512. Double-buffered 64-key K/V tiles, one barrier/iter,
// S^T formulation, no-shift softmax (Q pre-scaled), MFMA row-sums.
//   lsK [2 buf][2 dslab][64 r][32]   16KB  (stages Q in two 128-row passes)
//   lsV [2 buf][2 kslab][64 d][32]   16KB
//   lsP per-wave [64 q][32 k']       16KB
// R9: setprio(1) around QK^T and PV MFMA clusters (T5).
// ---------------------------------------------------------------------------
__global__ __launch_bounds__(256, 2) void attn_flash(const u16* __restrict__ Qh,
                                                     const u16* __restrict__ Kh,
                                                     const u16* __restrict__ Vt,
                                                     u16* __restrict__ Oh) {
  __shared__ __attribute__((aligned(16))) u16 lsK[2 * 2 * 64 * 32];
  __shared__ __attribute__((aligned(16))) u16 lsV[2 * 2 * 64 * 32];
  __shared__ __attribute__((aligned(16))) u16 lsP[4 * 64 * 32];
  const int tid = threadIdx.x;
  const int lane = tid & 63, wave = tid >> 6;
  const int l15 = lane & 15, quad = lane >> 4;
  const int sw = (l15 >> 1) & 3;
  const int qsw8 = (quad ^ sw) * 8;
  // XCD swizzle: a head's 8 q-tiles are 64 apart -> same XCD (idx%8 const).
  const int bh = blockIdx.x & 63, qt = blockIdx.x >> 6;  // qt in [0,8)
  const u16* Qb = Qh + ((long long)bh * 2048 + qt * 256) * 64;
  const u16* Kb = Kh + (long long)bh * 2048 * 64;
  const u16* Vb = Vt + (long long)bh * 64 * 2048;
  u16* lsPw = lsP + wave * 2048;

  // ---- stage Q in two 128-row passes via lsK [2 dslab][128 row][32] ----
  half8 qb[4][2];  // [qt2][dslab]
#pragma unroll
  for (int pass = 0; pass < 2; ++pass) {
#pragma unroll
    for (int i = 0; i < 4; ++i) {
      int c = i * 256 + tid;
      g2l16(Qb + (pass * 128 + ((c >> 2) & 127)) * 64 + (c >> 9) * 32 + swz(c) * 8,
            lsK + (i * 256 + wave * 64) * 8);
    }
    __syncthreads();
    if ((wave >> 1) == pass) {
      const int lrow = (wave & 1) * 64;
#pragma unroll
      for (int qt2 = 0; qt2 < 4; ++qt2)
#pragma unroll
        for (int ks = 0; ks < 2; ++ks)
          qb[qt2][ks] = *(const half8*)(lsK + ks * 4096 +
                                        (lrow + qt2 * 16 + l15) * 32 + qsw8);
    }
    __syncthreads();
  }

  // ---- stage K(0), V(0) into buf 0: 512 slots each, 2/thread ----
#pragma unroll
  for (int i = 0; i < 2; ++i) {
    int c = i * 256 + tid;
    g2l16(Kb + ((c >> 2) & 63) * 64 + (c >> 8) * 32 + swz(c) * 8,
          lsK + (i * 256 + wave * 64) * 8);
    g2l16(Vb + ((c >> 2) & 63) * 2048 + (c >> 8) * 32 + swz(c) * 8,
          lsV + (i * 256 + wave * 64) * 8);
  }

  half8 onesf;
#pragma unroll
  for (int j = 0; j < 8; ++j) onesf[j] = (_Float16)1.0f;

  floatx4 oacc[4][4] = {};  // [qt2][dt]
  floatx4 osum[4] = {};     // row-sums l, oacc row layout (via ones-MFMA)

  for (int kt = 0; kt < 32; ++kt) {
    const int cur = kt & 1;
    const u16* bufK = lsK + cur * 4096;
    const u16* bufV = lsV + cur * 4096;
    __syncthreads();
    if (kt < 31) {
      u16* nK = lsK + (1 - cur) * 4096;
      u16* nV = lsV + (1 - cur) * 4096;
#pragma unroll
      for (int i = 0; i < 2; ++i) {
        int c = i * 256 + tid;
        g2l16(Kb + (kt + 1) * 4096 + ((c >> 2) & 63) * 64 + (c >> 8) * 32 + swz(c) * 8,
              nK + (i * 256 + wave * 64) * 8);
        g2l16(Vb + ((c >> 2) & 63) * 2048 + (kt + 1) * 64 + (c >> 8) * 32 + swz(c) * 8,
              nV + (i * 256 + wave * 64) * 8);
      }
    }
#pragma unroll
    for (int ks4 = 0; ks4 < 2; ++ks4) {
      // ---- S^T for this 32-key slab: k = ks4*32 + h*16 + quad*4+r ----
      floatx4 sacc[2][4] = {};  // [h][qt2]
      __builtin_amdgcn_s_setprio(1);
#pragma unroll
      for (int ks = 0; ks < 2; ++ks) {
#pragma unroll
        for (int h = 0; h < 2; ++h) {
          half8 kf = *(const half8*)(bufK + ks * 2048 + ((ks4 * 2 + h) * 16 + l15) * 32 + qsw8);
#pragma unroll
          for (int qt2 = 0; qt2 < 4; ++qt2)
            sacc[h][qt2] = __builtin_amdgcn_mfma_f32_16x16x32_f16(kf, qb[qt2][ks], sacc[h][qt2], 0, 0, 0);
        }
      }
      __builtin_amdgcn_s_setprio(0);
      // ---- P = exp2(s) (Q pre-scaled), packed write ----
#pragma unroll
      for (int h = 0; h < 2; ++h) {
#pragma unroll
        for (int qt2 = 0; qt2 < 4; ++qt2) {
          float p0 = __builtin_amdgcn_exp2f(sacc[h][qt2][0]);
          float p1 = __builtin_amdgcn_exp2f(sacc[h][qt2][1]);
          float p2 = __builtin_amdgcn_exp2f(sacc[h][qt2][2]);
          float p3 = __builtin_amdgcn_exp2f(sacc[h][qt2][3]);
          union { fp16v2 h2; unsigned u; } lo, hi;
          lo.h2 = __builtin_amdgcn_cvt_pkrtz(p0, p1);
          hi.h2 = __builtin_amdgcn_cvt_pkrtz(p2, p3);
          uint2 pk = {lo.u, hi.u};
          *(uint2*)(lsPw + (qt2 * 16 + l15) * 32 +
                    (((2 * h + (quad >> 1)) ^ sw) * 8) + (quad & 1) * 4) = pk;
        }
      }
      // ---- PV + ones-MFMA row-sum ----
      half8 pa[4];
#pragma unroll
      for (int qt2 = 0; qt2 < 4; ++qt2)
        pa[qt2] = *(const half8*)(lsPw + (qt2 * 16 + l15) * 32 + qsw8);
      __builtin_amdgcn_s_setprio(1);
#pragma unroll
      for (int dt = 0; dt < 4; ++dt) {
        half8 vb = *(const half8*)(bufV + ks4 * 2048 + (dt * 16 + l15) * 32 + qsw8);
#pragma unroll
        for (int qt2 = 0; qt2 < 4; ++qt2)
          oacc[qt2][dt] = __builtin_amdgcn_mfma_f32_16x16x32_f16(pa[qt2], vb, oacc[qt2][dt], 0, 0, 0);
      }
#pragma unroll
      for (int qt2 = 0; qt2 < 4; ++qt2)
        osum[qt2] = __builtin_amdgcn_mfma_f32_16x16x32_f16(pa[qt2], onesf, osum[qt2], 0, 0, 0);
      __builtin_amdgcn_s_setprio(0);
    }
  }

  // ---- epilogue: O / l -> fp16 attn_out[B, N, H*64] ----
  const int b = bh >> 4, h = bh & 15;
#pragma unroll
  for (int qt2 = 0; qt2 < 4; ++qt2) {
#pragma unroll
    for (int r = 0; r < 4; ++r) {
      float inv = 1.0f / osum[qt2][r];
      int qrow = qt * 256 + wave * 64 + qt2 * 16 + quad * 4 + r;
      long long rowbase = ((long long)b * 2048 + qrow) * 1024 + h * 64;
#pragma unroll
      for (int dt = 0; dt < 4; ++dt)
        Oh[rowbase + dt * 16 + l15] = f2h(oacc[qt2][dt][r] * inv);
    }
  }
}

// ---------------------------------------------------------------------------
extern "C" void kernel_launch(void* const* d_in, const int* in_sizes, int n_in,
                              void* d_out, int out_size, void* d_ws, size_t ws_size,
                              hipStream_t stream) {
  const float* x = (const float*)d_in[0];      // [4,2048,1024]
  const float* Wqkv = (const float*)d_in[1];   // [1024,3072]
  const float* Wout = (const float*)d_in[2];   // [1024,1024]
  const float* bout = (const float*)d_in[3];   // [1024]
  float* out = (float*)d_out;                  // [4,2048,1024] fp32

  char* ws = (char*)d_ws;  // 88 MB used
  u16* Xh = (u16*)(ws);                          // 16 MB  [8192,1024]
  u16* Wqkvt = (u16*)(ws + (16ll << 20));        //  6 MB  [3072,1024]
  u16* Woutt = (u16*)(ws + (22ll << 20));        //  2 MB  [1024,1024]
  u16* Qh = (u16*)(ws + (24ll << 20));           // 16 MB  [B,H,2048,64] (pre-scaled)
  u16* Kh = (u16*)(ws + (40ll << 20));           // 16 MB  [B,H,2048,64]
  u16* Vt = (u16*)(ws + (56ll << 20));           // 16 MB  [B,H,64,2048]
  u16* Oh = (u16*)(ws + (72ll << 20));           // 16 MB  [8192,1024]

  cast_f32_f16<<<4096, 256, 0, stream>>>(x, Xh);
  transpose_cast<<<16 * 48, 256, 0, stream>>>(Wqkv, Wqkvt, 1024, 3072);
  transpose_cast<<<16 * 16, 256, 0, stream>>>(Wout, Woutt, 1024, 1024);
  gemm8p<0><<<768, 512, 0, stream>>>(Xh, Wqkvt, Qh, Kh, Vt, nullptr, nullptr);
  attn_flash<<<512, 256, 0, stream>>>(Qh, Kh, Vt, Oh);
  gemm8p<1><<<256, 512, 0, stream>>>(Oh, Woutt, nullptr, nullptr, nullptr, out, bout);
}